// Round 7
// baseline (379.513 us; speedup 1.0000x reference)
//
#include <hip/hip_runtime.h>

#define NN 4096
#define EE 131072
#define NP1 2048
#define NP2 1024

typedef __attribute__((ext_vector_type(8))) __bf16 bf16x8;
typedef __attribute__((ext_vector_type(4))) float f32x4;
typedef __attribute__((ext_vector_type(8))) unsigned short ushort8;

static __device__ inline unsigned short bfbits(__bf16 b) {
  union { __bf16 x; unsigned short u; } c; c.x = b; return c.u;
}
static __device__ inline void split2(float v, unsigned short& h, unsigned short& l) {
  __bf16 hb = (__bf16)v;
  float hf = (float)hb;
  __bf16 lb = (__bf16)(v - hf);
  h = bfbits(hb); l = bfbits(lb);
}

// Packed fragment layout for a [R rows][K k] bf16 matrix (R%16==0, K%32==0):
// 16x32 tile (rt,kt) holds 64 chunks of 8 elems; chunk-in-tile = ((k>>3)&3)*16 + (r&15)
// == the MFMA lane id, so a wave's fragment load is 64 lanes * 16B contiguous.
static __device__ inline size_t pchunk(int r, int k, int NT) {
  return ((size_t)(r >> 4) * NT + (k >> 5)) * 64 + (((k >> 3) & 3) << 4) + (r & 15);
}

// ---------------- graph build ----------------

__global__ void hist_kernel(const int* __restrict__ src, const int* __restrict__ dst,
                            int* __restrict__ cnt_src, int* __restrict__ cnt_dst, int E) {
  int e = blockIdx.x * blockDim.x + threadIdx.x;
  if (e < E) {
    atomicAdd(&cnt_src[src[e]], 1);
    atomicAdd(&cnt_dst[dst[e]], 1);
  }
}

__global__ __launch_bounds__(1024) void scan_kernel(const int* __restrict__ in, int* __restrict__ out, int n) {
  __shared__ int tmp[4096];
  int tid = threadIdx.x;
  for (int i = tid; i < n; i += 1024) tmp[i] = in[i];
  __syncthreads();
  for (int off = 1; off < n; off <<= 1) {
    int v[4];
    int c = 0;
    for (int i = tid; i < n; i += 1024) { v[c++] = (i >= off) ? tmp[i - off] : 0; }
    __syncthreads();
    c = 0;
    for (int i = tid; i < n; i += 1024) { tmp[i] += v[c++]; }
    __syncthreads();
  }
  for (int i = tid; i < n; i += 1024) out[i + 1] = tmp[i];
  if (tid == 0) out[0] = 0;
}

__global__ void scatter_kernel(const int* __restrict__ src, const int* __restrict__ dst,
                               const int* __restrict__ csc_off, const int* __restrict__ csr_off,
                               int* __restrict__ fill_dst, int* __restrict__ fill_src,
                               int* __restrict__ csc_src, int* __restrict__ csr_dst, int E) {
  int e = blockIdx.x * blockDim.x + threadIdx.x;
  if (e < E) {
    int s = src[e], d = dst[e];
    int p = atomicAdd(&fill_dst[d], 1);
    csc_src[csc_off[d] + p] = s;
    int q = atomicAdd(&fill_src[s], 1);
    csr_dst[csr_off[s] + q] = d;
  }
}

__global__ void dis0_kernel(const int* __restrict__ cnt_dst, float* __restrict__ dis, int n) {
  int i = blockIdx.x * blockDim.x + threadIdx.x;
  if (i < n) dis[i] = rsqrtf((float)cnt_dst[i] + 1.0f);
}

__global__ void pnorm_kernel(const float* __restrict__ p, float* __restrict__ outv, int C) {
  int tid = threadIdx.x;
  float acc = 0.f;
  for (int j = tid; j < C; j += 256) { float v = p[j]; acc += v * v; }
  for (int o = 32; o > 0; o >>= 1) acc += __shfl_down(acc, o);
  __shared__ float red[4];
  if ((tid & 63) == 0) red[tid >> 6] = acc;
  __syncthreads();
  if (tid == 0) outv[0] = sqrtf(red[0] + red[1] + red[2] + red[3]);
}

// ---------------- scoring / topk ----------------

__global__ void score_key(const float* __restrict__ X, const float* __restrict__ p,
                          const float* __restrict__ pn, float* __restrict__ s,
                          unsigned long long* __restrict__ keys, int C) {
  int i = blockIdx.x;
  int tid = threadIdx.x;
  float acc = 0.f;
  for (int j = tid; j < C; j += 256) acc += X[(size_t)i * C + j] * p[j];
  for (int o = 32; o > 0; o >>= 1) acc += __shfl_down(acc, o);
  __shared__ float red[4];
  if ((tid & 63) == 0) red[tid >> 6] = acc;
  __syncthreads();
  if (tid == 0) {
    float sv = tanhf((red[0] + red[1] + red[2] + red[3]) / pn[0]);
    s[i] = sv;
    unsigned u = __float_as_uint(sv);
    unsigned m = (u & 0x80000000u) ? ~u : (u | 0x80000000u);
    keys[i] = (((unsigned long long)(~m)) << 32) | (unsigned)i;  // desc value, asc index
  }
}

__global__ __launch_bounds__(256) void rank_count(const unsigned long long* __restrict__ keys,
                                                  int* __restrict__ rank) {
  __shared__ unsigned long long kk[512];
  int tid = threadIdx.x;
  int cand = blockIdx.x * 256 + tid;
  int base = blockIdx.y * 512;
  kk[tid] = keys[base + tid];
  kk[tid + 256] = keys[base + tid + 256];
  __syncthreads();
  unsigned long long kc = keys[cand];
  int c = 0;
#pragma unroll 8
  for (int t = 0; t < 512; ++t) c += (kk[t] < kc) ? 1 : 0;
  atomicAdd(&rank[cand], c);
}

__global__ void rank_place(const float* __restrict__ s, const int* __restrict__ rank, int k, int n,
                           int* __restrict__ kept, int* __restrict__ perm, float* __restrict__ vals) {
  int i = blockIdx.x * blockDim.x + threadIdx.x;
  if (i < n) {
    int r = rank[i];
    if (r < k) { perm[r] = i; vals[r] = s[i]; kept[i] = r; }
    else kept[i] = -1;
  }
}

// pooled row gather + gate + bf16 split into PACKED layout
__global__ void pool_split_p(const float* __restrict__ X, const int* __restrict__ perm,
                             const float* __restrict__ vals, unsigned short* __restrict__ h,
                             unsigned short* __restrict__ l, int C) {
  int a = blockIdx.x;
  int r = perm[a];
  float v = vals[a];
  int NT = C >> 5;
  for (int j0 = threadIdx.x * 8; j0 < C; j0 += 64 * 8) {
    ushort8 hv, lv;
#pragma unroll
    for (int e = 0; e < 8; ++e) {
      unsigned short he, le;
      split2(X[(size_t)r * C + j0 + e] * v, he, le);
      hv[e] = he; lv[e] = le;
    }
    size_t c = pchunk(a, j0, NT);
    *(ushort8*)&h[c * 8] = hv;
    *(ushort8*)&l[c * 8] = lv;
  }
}

// ---------------- augment: row-parallel SpGEMM with LDS accumulator ----------------

__global__ __launch_bounds__(256) void aug_row(const int* __restrict__ csr_off,
                                               const int* __restrict__ csr_dst,
                                               const int* __restrict__ kept,
                                               const int* __restrict__ perm,
                                               float* __restrict__ B) {
  __shared__ float acc[NP1];
  int ki = blockIdx.x;
  int r = perm[ki];
  for (int t = threadIdx.x; t < NP1; t += 256) acc[t] = 0.f;
  __syncthreads();
  int s = csr_off[r], e = csr_off[r + 1];
  int nm = e - s;
  int wave = threadIdx.x >> 6, lane = threadIdx.x & 63;
  for (int m = wave; m <= nm; m += 4) {
    int k = (m < nm) ? csr_dst[s + m] : r;
    int s2 = csr_off[k], e2 = csr_off[k + 1];
    int n2 = e2 - s2;
    for (int t = lane; t <= n2; t += 64) {
      int j = (t < n2) ? csr_dst[s2 + t] : k;
      int kj = kept[j];
      if (kj >= 0) atomicAdd(&acc[kj], 1.0f);
    }
  }
  __syncthreads();
  if (threadIdx.x == 0) acc[ki] += 1.0f;
  __syncthreads();
  float* row = B + (size_t)ki * NP1;
  for (int t = threadIdx.x; t < NP1; t += 256) row[t] = acc[t];
}

__global__ void colsum_part(const float* __restrict__ B, float* __restrict__ deg, int n) {
  int c = blockIdx.x * blockDim.x + threadIdx.x;
  int r0 = blockIdx.y * 16;
  float acc = 0.f;
#pragma unroll
  for (int r = 0; r < 16; ++r) acc += B[(size_t)(r0 + r) * n + c];
  atomicAdd(&deg[c], acc);
}

__global__ void dis_from_deg(const float* __restrict__ deg, float* __restrict__ dis, int n) {
  int i = blockIdx.x * blockDim.x + threadIdx.x;
  if (i < n) dis[i] = rsqrtf(deg[i]);
}

// ---------------- conversions (all emit packed layout) ----------------

__global__ void split_p(const float* __restrict__ in, unsigned short* __restrict__ h,
                        unsigned short* __restrict__ l, int K) {
  int c = blockIdx.x * blockDim.x + threadIdx.x;  // chunk index
  int lane = c & 63, tile = c >> 6;
  int NT = K >> 5;
  int kt = tile % NT, rt = tile / NT;
  int r = rt * 16 + (lane & 15);
  int k = kt * 32 + (lane >> 4) * 8;
  const float* p = in + (size_t)r * K + k;
  ushort8 hv, lv;
#pragma unroll
  for (int e = 0; e < 8; ++e) {
    unsigned short he, le;
    split2(p[e], he, le);
    hv[e] = he; lv[e] = le;
  }
  *(ushort8*)&h[(size_t)c * 8] = hv;
  *(ushort8*)&l[(size_t)c * 8] = lv;
}

__global__ void tsplit_p(const float* __restrict__ in, unsigned short* __restrict__ oh,
                         unsigned short* __restrict__ ol, int R, int C) {
  int c = blockIdx.x * blockDim.x + threadIdx.x;
  int lane = c & 63, tile = c >> 6;
  int NT = R >> 5;
  int kt = tile % NT, jt = tile / NT;
  int j = jt * 16 + (lane & 15);
  int k = kt * 32 + (lane >> 4) * 8;
  ushort8 hv, lv;
#pragma unroll
  for (int e = 0; e < 8; ++e) {
    unsigned short he, le;
    split2(in[(size_t)(k + e) * C + j], he, le);
    hv[e] = he; lv[e] = le;
  }
  *(ushort8*)&oh[(size_t)c * 8] = hv;
  *(ushort8*)&ol[(size_t)c * 8] = lv;
}

__global__ __launch_bounds__(256) void b1_dual_p(const float* __restrict__ in,
                                                 unsigned short* __restrict__ rm,
                                                 unsigned short* __restrict__ tr, int n) {
  __shared__ float t[64][65];
  int r0 = blockIdx.y * 64, c0 = blockIdx.x * 64;
  int tid = threadIdx.x;
  int NT = n >> 5;
#pragma unroll
  for (int q = 0; q < 16; ++q) {
    int idx = q * 256 + tid;
    int rr = idx >> 6, cc = idx & 63;
    t[rr][cc] = in[(size_t)(r0 + rr) * n + c0 + cc];
  }
  __syncthreads();
#pragma unroll
  for (int q2 = tid; q2 < 512; q2 += 256) {
    int rr = q2 >> 3, cc8 = q2 & 7;
    ushort8 hv;
#pragma unroll
    for (int e = 0; e < 8; ++e) hv[e] = bfbits((__bf16)t[rr][cc8 * 8 + e]);
    *(ushort8*)&rm[pchunk(r0 + rr, c0 + cc8 * 8, NT) * 8] = hv;
  }
#pragma unroll
  for (int q2 = tid; q2 < 512; q2 += 256) {
    int cc = q2 >> 3, rr8 = q2 & 7;
    ushort8 hv;
#pragma unroll
    for (int e = 0; e < 8; ++e) hv[e] = bfbits((__bf16)t[rr8 * 8 + e][cc]);
    *(ushort8*)&tr[pchunk(c0 + cc, r0 + rr8 * 8, NT) * 8] = hv;
  }
}

__global__ void gather_p(const unsigned short* __restrict__ in, const int* __restrict__ perm,
                         unsigned short* __restrict__ outp, int NT) {
  int c = blockIdx.x * blockDim.x + threadIdx.x;
  int lane = c & 63, tile = c >> 6;
  int kt = tile % NT, at = tile / NT;
  int a = at * 16 + (lane & 15);
  int sub = lane >> 4;
  int p = perm[a];
  size_t sc = ((size_t)(p >> 4) * NT + kt) * 64 + sub * 16 + (p & 15);
  *(ushort8*)&outp[(size_t)c * 8] = *(const ushort8*)&in[sc * 8];
}

__global__ void unpool_split_p(const float* __restrict__ res, const float* __restrict__ up,
                               const int* __restrict__ kept, unsigned short* __restrict__ h,
                               unsigned short* __restrict__ l, int C) {
  int c = blockIdx.x * blockDim.x + threadIdx.x;
  int lane = c & 63, tile = c >> 6;
  int NT = C >> 5;
  int kt = tile % NT, rt = tile / NT;
  int r = rt * 16 + (lane & 15);
  int j0 = kt * 32 + (lane >> 4) * 8;
  int kv = kept[r];
  ushort8 hv, lv;
#pragma unroll
  for (int e = 0; e < 8; ++e) {
    float v = res[(size_t)r * C + j0 + e];
    if (kv >= 0) v += up[(size_t)kv * C + j0 + e];
    unsigned short he, le;
    split2(v, he, le);
    hv[e] = he; lv[e] = le;
  }
  *(ushort8*)&h[(size_t)c * 8] = hv;
  *(ushort8*)&l[(size_t)c * 8] = lv;
}

// ---------------- misc ----------------

template <int C>
__global__ __launch_bounds__(256) void spmm_gather_v(const float* __restrict__ Y,
                                                     const int* __restrict__ off,
                                                     const int* __restrict__ srcs,
                                                     const float* __restrict__ dis,
                                                     const float* __restrict__ bias,
                                                     float* __restrict__ out) {
  constexpr int VEC = C / 64;
  int w = threadIdx.x >> 6, lane = threadIdx.x & 63;
  int c = blockIdx.x * 4 + w;
  int j = lane * VEC;
  float acc[VEC];
  const float* p = Y + (size_t)c * C + j;
#pragma unroll
  for (int u = 0; u < VEC; ++u) acc[u] = p[u];
  int s = off[c], e = off[c + 1];
  for (int t = s; t < e; ++t) {
    const float* q = Y + (size_t)srcs[t] * C + j;
#pragma unroll
    for (int u = 0; u < VEC; ++u) acc[u] += q[u];
  }
  float d = dis[c];
  float* o = out + (size_t)c * C + j;
#pragma unroll
  for (int u = 0; u < VEC; ++u) o[u] = fmaxf(d * acc[u] + bias[j + u], 0.0f);
}

// split-K combine: out = relu(rs*(sum of S partials) + bias)
template <int S>
__global__ void ep3(const float* __restrict__ p, const float* __restrict__ rs,
                    const float* __restrict__ bias, float* __restrict__ outp, int M, int N) {
  int idx = blockIdx.x * blockDim.x + threadIdx.x;
  int j4 = (idx * 4) % N, i = (idx * 4) / N;
  float4 a = {0.f, 0.f, 0.f, 0.f};
#pragma unroll
  for (int s = 0; s < S; ++s) {
    float4 b = *(const float4*)(p + ((size_t)s * M + i) * N + j4);
    a.x += b.x; a.y += b.y; a.z += b.z; a.w += b.w;
  }
  float r = rs[i];
  float4 o;
  o.x = fmaxf(r * a.x + bias[j4 + 0], 0.f);
  o.y = fmaxf(r * a.y + bias[j4 + 1], 0.f);
  o.z = fmaxf(r * a.z + bias[j4 + 2], 0.f);
  o.w = fmaxf(r * a.w + bias[j4 + 3], 0.f);
  *(float4*)(outp + (size_t)i * N + j4) = o;
}

// split-K combine for augment: B = sum of S partials (+I)
template <int S>
__global__ void ep_aug(const float* __restrict__ p, float* __restrict__ B, int n) {
  int idx = blockIdx.x * blockDim.x + threadIdx.x;
  int j4 = (idx * 4) % n, i = (idx * 4) / n;
  float4 a = {0.f, 0.f, 0.f, 0.f};
#pragma unroll
  for (int s = 0; s < S; ++s) {
    float4 b = *(const float4*)(p + ((size_t)s * n + i) * n + j4);
    a.x += b.x; a.y += b.y; a.z += b.z; a.w += b.w;
  }
  if (i >= j4 && i < j4 + 4) (&a.x)[i - j4] += 1.0f;
  *(float4*)(B + (size_t)i * n + j4) = a;
}

// ---------------- bf16-split MFMA GEMM, 32x32/wave (small/xw cases) ----------------
// S>1: partial to C + z*M*N. S==1 EPI: 0 plain; 1 rowscale; 2 rowscale + packed-split transpose out
template <int EPI, int AL, int BL, int KK, int S>
__global__ __launch_bounds__(256) void gemm16(
    const unsigned short* __restrict__ Ah, const unsigned short* __restrict__ Al,
    const unsigned short* __restrict__ Bh, const unsigned short* __restrict__ Bl,
    int M, int N, const float* __restrict__ rs,
    float* __restrict__ C, unsigned short* __restrict__ Th, unsigned short* __restrict__ Tl) {
  static_assert(KK % 32 == 0, "K");
  constexpr int KSTEPS = KK / 32;
  const int NT = (KK * S) >> 5;
  const int gx = gridDim.x;
  int id = blockIdx.y * gx + blockIdx.x;
  int cpx = (gx * gridDim.y) >> 3;
  int sid = (id & 7) * cpx + (id >> 3);
  const int bx = sid % gx, by = sid / gx;
  const int z = (S > 1) ? blockIdx.z : 0;
  const int wid = threadIdx.x >> 6, lane = threadIdx.x & 63;
  const int i0 = by * 64 + (wid >> 1) * 32;
  const int j0 = bx * 64 + (wid & 1) * 32;
  const int lr = lane & 15, lk = lane >> 4;
  size_t aoff[2], boff[2];
#pragma unroll
  for (int t = 0; t < 2; ++t) {
    aoff[t] = ((size_t)((i0 >> 4) + t) * NT + z * (KK >> 5)) * 512 + lane * 8;
    boff[t] = ((size_t)((j0 >> 4) + t) * NT + z * (KK >> 5)) * 512 + lane * 8;
  }
  const f32x4 zf = {0.f, 0.f, 0.f, 0.f};
  f32x4 acc[2][2];
  acc[0][0] = zf; acc[0][1] = zf; acc[1][0] = zf; acc[1][1] = zf;

  bf16x8 ahf[4][2], bhf[4][2], alf[4][2], blf[4][2];
  auto loadk = [&](int kk, int b) {
    size_t o = (size_t)kk * 512;
    ahf[b][0] = *(const bf16x8*)(Ah + aoff[0] + o);
    ahf[b][1] = *(const bf16x8*)(Ah + aoff[1] + o);
    bhf[b][0] = *(const bf16x8*)(Bh + boff[0] + o);
    bhf[b][1] = *(const bf16x8*)(Bh + boff[1] + o);
    if constexpr (AL) {
      alf[b][0] = *(const bf16x8*)(Al + aoff[0] + o);
      alf[b][1] = *(const bf16x8*)(Al + aoff[1] + o);
    }
    if constexpr (BL) {
      blf[b][0] = *(const bf16x8*)(Bl + boff[0] + o);
      blf[b][1] = *(const bf16x8*)(Bl + boff[1] + o);
    }
  };
  auto domm = [&](int b) {
#pragma unroll
    for (int am = 0; am < 2; ++am)
#pragma unroll
      for (int bn = 0; bn < 2; ++bn) {
        acc[am][bn] = __builtin_amdgcn_mfma_f32_16x16x32_bf16(ahf[b][am], bhf[b][bn], acc[am][bn], 0, 0, 0);
        if constexpr (BL)
          acc[am][bn] = __builtin_amdgcn_mfma_f32_16x16x32_bf16(ahf[b][am], blf[b][bn], acc[am][bn], 0, 0, 0);
        if constexpr (AL)
          acc[am][bn] = __builtin_amdgcn_mfma_f32_16x16x32_bf16(alf[b][am], bhf[b][bn], acc[am][bn], 0, 0, 0);
      }
  };

  loadk(0, 0);
  if constexpr (KSTEPS > 1) loadk(1, 1);
  if constexpr (KSTEPS > 2) loadk(2, 2);
#pragma unroll
  for (int kk = 0; kk < KSTEPS; ++kk) {
    const int cur = kk & 3;
    if (kk + 3 < KSTEPS) loadk(kk + 3, (cur + 3) & 3);
    domm(cur);
  }

#pragma unroll
  for (int am = 0; am < 2; ++am)
#pragma unroll
    for (int bn = 0; bn < 2; ++bn) {
      int ib = i0 + 16 * am + lk * 4;
      int j = j0 + 16 * bn + lr;
      f32x4 a = acc[am][bn];
      if constexpr (S > 1) {
#pragma unroll
        for (int r = 0; r < 4; ++r) C[((size_t)z * M + ib + r) * N + j] = a[r];
      } else if constexpr (EPI == 0) {
#pragma unroll
        for (int r = 0; r < 4; ++r) C[(size_t)(ib + r) * N + j] = a[r];
      } else if constexpr (EPI == 1) {
#pragma unroll
        for (int r = 0; r < 4; ++r) C[(size_t)(ib + r) * N + j] = rs[ib + r] * a[r];
      } else {
        unsigned long long hp = 0, lp = 0;
#pragma unroll
        for (int r = 0; r < 4; ++r) {
          unsigned short hv, lv;
          split2(rs[ib + r] * a[r], hv, lv);
          hp |= ((unsigned long long)hv) << (16 * r);
          lp |= ((unsigned long long)lv) << (16 * r);
        }
        size_t c = pchunk(j, ib, M >> 5);
        *(unsigned long long*)&Th[c * 8 + (ib & 7)] = hp;
        *(unsigned long long*)&Tl[c * 8 + (ib & 7)] = lp;
      }
    }
}

// ---------------- bf16-split MFMA GEMM, 64x64/wave (big aggregation GEMMs) ----------------
// Block = 2x2 waves = 128x128 tile; always split-K partial output to C + z*M*N.
template <int AL, int BL, int KK, int S>
__global__ __launch_bounds__(256) void gemm64(
    const unsigned short* __restrict__ Ah, const unsigned short* __restrict__ Al,
    const unsigned short* __restrict__ Bh, const unsigned short* __restrict__ Bl,
    int M, int N, float* __restrict__ C) {
  static_assert(KK % 32 == 0, "K");
  constexpr int KSTEPS = KK / 32;
  const int NT = (KK * S) >> 5;
  const int gx = gridDim.x;
  int id = blockIdx.y * gx + blockIdx.x;
  int cpx = (gx * gridDim.y) >> 3;
  int sid = (id & 7) * cpx + (id >> 3);
  const int bx = sid % gx, by = sid / gx;
  const int z = blockIdx.z;
  const int wid = threadIdx.x >> 6, lane = threadIdx.x & 63;
  const int i0 = by * 128 + (wid >> 1) * 64;
  const int j0 = bx * 128 + (wid & 1) * 64;
  const int lr = lane & 15, lk = lane >> 4;
  size_t aoff[4], boff[4];
#pragma unroll
  for (int t = 0; t < 4; ++t) {
    aoff[t] = ((size_t)((i0 >> 4) + t) * NT + z * (KK >> 5)) * 512 + lane * 8;
    boff[t] = ((size_t)((j0 >> 4) + t) * NT + z * (KK >> 5)) * 512 + lane * 8;
  }
  const f32x4 zf = {0.f, 0.f, 0.f, 0.f};
  f32x4 acc[4][4];
#pragma unroll
  for (int a = 0; a < 4; ++a)
#pragma unroll
    for (int b = 0; b < 4; ++b) acc[a][b] = zf;

  bf16x8 ahf[2][4], bhf[2][4], alf[2][4], blf[2][4];
  auto loadk = [&](int kk, int b) {
    size_t o = (size_t)kk * 512;
#pragma unroll
    for (int t = 0; t < 4; ++t) {
      ahf[b][t] = *(const bf16x8*)(Ah + aoff[t] + o);
      bhf[b][t] = *(const bf16x8*)(Bh + boff[t] + o);
      if constexpr (AL) alf[b][t] = *(const bf16x8*)(Al + aoff[t] + o);
      if constexpr (BL) blf[b][t] = *(const bf16x8*)(Bl + boff[t] + o);
    }
  };
  auto domm = [&](int b) {
#pragma unroll
    for (int am = 0; am < 4; ++am)
#pragma unroll
      for (int bn = 0; bn < 4; ++bn) {
        acc[am][bn] = __builtin_amdgcn_mfma_f32_16x16x32_bf16(ahf[b][am], bhf[b][bn], acc[am][bn], 0, 0, 0);
        if constexpr (BL)
          acc[am][bn] = __builtin_amdgcn_mfma_f32_16x16x32_bf16(ahf[b][am], blf[b][bn], acc[am][bn], 0, 0, 0);
        if constexpr (AL)
          acc[am][bn] = __builtin_amdgcn_mfma_f32_16x16x32_bf16(alf[b][am], bhf[b][bn], acc[am][bn], 0, 0, 0);
      }
  };

  loadk(0, 0);
#pragma unroll
  for (int kk = 0; kk < KSTEPS; ++kk) {
    const int cur = kk & 1;
    if (kk + 1 < KSTEPS) loadk(kk + 1, cur ^ 1);
    domm(cur);
  }

#pragma unroll
  for (int am = 0; am < 4; ++am)
#pragma unroll
    for (int bn = 0; bn < 4; ++bn) {
      int ib = i0 + 16 * am + lk * 4;
      int j = j0 + 16 * bn + lr;
      f32x4 a = acc[am][bn];
#pragma unroll
      for (int r = 0; r < 4; ++r) C[((size_t)z * M + ib + r) * N + j] = a[r];
    }
}

// ---------------- launch ----------------

extern "C" void kernel_launch(void* const* d_in, const int* in_sizes, int n_in,
                              void* d_out, int out_size, void* d_ws, size_t ws_size,
                              hipStream_t stream) {
  (void)in_sizes; (void)n_in; (void)out_size; (void)ws_size;
  const float* x  = (const float*)d_in[0];
  const int* ei   = (const int*)d_in[1];
  const int* esrc = ei;
  const int* edst = ei + EE;
  const float* w0 = (const float*)d_in[2];
  const float* b0 = (const float*)d_in[3];
  const float* w1 = (const float*)d_in[4];
  const float* b1 = (const float*)d_in[5];
  const float* w2 = (const float*)d_in[6];
  const float* b2 = (const float*)d_in[7];
  const float* w3 = (const float*)d_in[8];
  const float* b3 = (const float*)d_in[9];
  const float* w4 = (const float*)d_in[10];
  const float* b4 = (const float*)d_in[11];
  const float* p0 = (const float*)d_in[12];
  const float* p1 = (const float*)d_in[13];
  float* out = (float*)d_out;

  char* ws = (char*)d_ws;
  size_t off = 0;
  auto alloc = [&](size_t b) { void* p = ws + off; off += (b + 255) & ~(size_t)255; return p; };

  int* csc_off = (int*)alloc(4 * (NN + 1));
  int* csr_off = (int*)alloc(4 * (NN + 1));
  int* csc_src = (int*)alloc(4 * EE);
  int* csr_dst = (int*)alloc(4 * EE);

  size_t zero_bytes = 4 * NN * 4 + 4 * NP1 + 4 * NP2 + 4 * NN + 4 * NP1;
  int* cnts    = (int*)alloc(zero_bytes);
  int* cnt_dst = cnts;
  int* cnt_src = cnts + NN;
  int* fill_dst = cnts + 2 * NN;
  int* fill_src = cnts + 3 * NN;
  float* deg1 = (float*)(cnts + 4 * NN);
  float* deg2 = deg1 + NP1;
  int* rank0 = (int*)(deg2 + NP2);
  int* rank1 = rank0 + NN;

  int* kept0 = (int*)alloc(4 * NN);
  int* perm0 = (int*)alloc(4 * NP1);
  int* kept1 = (int*)alloc(4 * NP1);
  int* perm1 = (int*)alloc(4 * NP2);
  float* dis0 = (float*)alloc(4 * NN);
  float* dis1 = (float*)alloc(4 * NP1);
  float* dis2 = (float*)alloc(4 * NP2);
  float* pnrm = (float*)alloc(8);
  float* s0   = (float*)alloc(4 * NN);
  float* vals0 = (float*)alloc(4 * NP1);
  float* s1   = (float*)alloc(4 * NP1);
  float* vals1 = (float*)alloc(4 * NP2);
  unsigned long long* keys0 = (unsigned long long*)alloc(8 * NN);
  unsigned long long* keys1 = (unsigned long long*)alloc(8 * NP1);

  const size_t MB = 1024 * 1024;
  // B1 region (16MB): B1 fp32 until b1_dual_p; then Gh/Hh gathers (0..8MB);
  // then B2 fp32 (0..4MB) + B2t splits (4..8MB).
  char* regB1 = (char*)alloc(16 * MB);
  float* B1   = (float*)regB1;
  unsigned short* Gh = (unsigned short*)regB1;            // 4MB gathered B1rm_p rows
  unsigned short* Hh = (unsigned short*)(regB1 + 4 * MB); // 4MB gathered B1t_p rows
  float* B2   = (float*)regB1;                            // after Gh dead
  unsigned short* B2th = (unsigned short*)(regB1 + 4 * MB);
  unsigned short* B2tl = (unsigned short*)(regB1 + 6 * MB);
  float* pscr = (float*)alloc(16 * MB);                   // split-K partials (up to 8 x 2MB etc.)

  unsigned short* B1rm = (unsigned short*)alloc(8 * MB);  // packed bf16 (exact)
  unsigned short* B1t  = (unsigned short*)alloc(8 * MB);  // packed bf16 transpose (exact)
  float* res0 = (float*)alloc(4 * MB);
  float* res1 = (float*)alloc(4 * MB);
  float* yreg = (float*)alloc(4 * MB);
  float* outreg = (float*)alloc(2 * MB);
  float* out2 = outreg, *out3 = outreg;
  char* ytreg = (char*)alloc(4 * MB);
  unsigned short* Y1th = (unsigned short*)ytreg;
  unsigned short* Y1tl = (unsigned short*)(ytreg + 2 * MB);
  unsigned short* Y2th = (unsigned short*)ytreg;
  unsigned short* Y2tl = (unsigned short*)(ytreg + 1 * MB);
  unsigned short* Y3th = (unsigned short*)ytreg;
  unsigned short* Y3tl = (unsigned short*)(ytreg + 1 * MB);
  char* xsreg = (char*)alloc(4 * MB);
  unsigned short* x3h = (unsigned short*)xsreg;
  unsigned short* x3l = (unsigned short*)(xsreg + 2 * MB);
  unsigned short* x4h = (unsigned short*)xsreg;
  unsigned short* x4l = (unsigned short*)(xsreg + 2 * MB);
  unsigned short* xh = (unsigned short*)alloc(1 * MB);
  unsigned short* xl = (unsigned short*)alloc(1 * MB);
  char* xsm = (char*)alloc(2 * MB);
  unsigned short* x1h = (unsigned short*)xsm;
  unsigned short* x1l = (unsigned short*)(xsm + 1 * MB);
  unsigned short* x2h = (unsigned short*)xsm;
  unsigned short* x2l = (unsigned short*)(xsm + 1 * MB);
  unsigned short* Wt0h = (unsigned short*)alloc(256 * 128 * 2);
  unsigned short* Wt0l = (unsigned short*)alloc(256 * 128 * 2);
  unsigned short* Wt1h = (unsigned short*)alloc(512 * 256 * 2);
  unsigned short* Wt1l = (unsigned short*)alloc(512 * 256 * 2);
  unsigned short* Wt2h = (unsigned short*)alloc(512 * 512 * 2);
  unsigned short* Wt2l = (unsigned short*)alloc(512 * 512 * 2);
  unsigned short* Wt3h = (unsigned short*)alloc(256 * 512 * 2);
  unsigned short* Wt3l = (unsigned short*)alloc(256 * 512 * 2);
  unsigned short* Wt4h = (unsigned short*)alloc(128 * 256 * 2);
  unsigned short* Wt4l = (unsigned short*)alloc(128 * 256 * 2);

  hipMemsetAsync(cnts, 0, zero_bytes, stream);

  // graph build
  hist_kernel<<<EE / 256, 256, 0, stream>>>(esrc, edst, cnt_src, cnt_dst, EE);
  scan_kernel<<<1, 1024, 0, stream>>>(cnt_dst, csc_off, NN);
  scan_kernel<<<1, 1024, 0, stream>>>(cnt_src, csr_off, NN);
  scatter_kernel<<<EE / 256, 256, 0, stream>>>(esrc, edst, csc_off, csr_off,
                                               fill_dst, fill_src, csc_src, csr_dst, EE);
  dis0_kernel<<<NN / 256, 256, 0, stream>>>(cnt_dst, dis0, NN);
  pnorm_kernel<<<1, 256, 0, stream>>>(p0, pnrm + 0, 256);
  pnorm_kernel<<<1, 256, 0, stream>>>(p1, pnrm + 1, 512);

  // operand conversions (packed)
  tsplit_p<<<(256 * 128 / 8) / 256, 256, 0, stream>>>(w0, Wt0h, Wt0l, 128, 256);
  tsplit_p<<<(512 * 256 / 8) / 256, 256, 0, stream>>>(w1, Wt1h, Wt1l, 256, 512);
  tsplit_p<<<(512 * 512 / 8) / 256, 256, 0, stream>>>(w2, Wt2h, Wt2l, 512, 512);
  tsplit_p<<<(256 * 512 / 8) / 256, 256, 0, stream>>>(w3, Wt3h, Wt3l, 512, 256);
  tsplit_p<<<(128 * 256 / 8) / 256, 256, 0, stream>>>(w4, Wt4h, Wt4l, 256, 128);
  split_p<<<(NN * 128 / 8) / 256, 256, 0, stream>>>(x, xh, xl, 128);

  // gcn0
  gemm16<1, 1, 1, 128, 1><<<dim3(4, 64), 256, 0, stream>>>(xh, xl, Wt0h, Wt0l,
                                                           NN, 256, dis0, yreg, nullptr, nullptr);
  spmm_gather_v<256><<<NN / 4, 256, 0, stream>>>(yreg, csc_off, csc_src, dis0, b0, res0);

  // pool0
  score_key<<<NN, 256, 0, stream>>>(res0, p0, pnrm + 0, s0, keys0, 256);
  rank_count<<<dim3(NN / 256, NN / 512), 256, 0, stream>>>(keys0, rank0);
  rank_place<<<NN / 256, 256, 0, stream>>>(s0, rank0, NP1, NN, kept0, perm0, vals0);
  pool_split_p<<<NP1, 64, 0, stream>>>(res0, perm0, vals0, x1h, x1l, 256);

  // augment0 -> B1 (+I folded), deg, dis; packed bf16 copies
  aug_row<<<NP1, 256, 0, stream>>>(csr_off, csr_dst, kept0, perm0, B1);
  colsum_part<<<dim3(NP1 / 256, NP1 / 16), 256, 0, stream>>>(B1, deg1, NP1);
  dis_from_deg<<<NP1 / 256, 256, 0, stream>>>(deg1, dis1, NP1);
  b1_dual_p<<<dim3(32, 32), 256, 0, stream>>>(B1, B1rm, B1t, NP1);
  // B1 fp32 dead after b1_dual_p.

  // gcn1
  gemm16<2, 1, 1, 256, 1><<<dim3(8, 32), 256, 0, stream>>>(x1h, x1l, Wt1h, Wt1l,
                                                           NP1, 512, dis1, nullptr, Y1th, Y1tl);
  gemm64<0, 1, 512, 4><<<dim3(4, 16, 4), 256, 0, stream>>>(B1t, nullptr, Y1th, Y1tl,
                                                           NP1, 512, pscr);
  ep3<4><<<(NP1 * 512) / 1024, 256, 0, stream>>>(pscr, dis1, b1, res1, NP1, 512);

  // pool1
  score_key<<<NP1, 256, 0, stream>>>(res1, p1, pnrm + 1, s1, keys1, 512);
  rank_count<<<dim3(NP1 / 256, NP1 / 512), 256, 0, stream>>>(keys1, rank1);
  rank_place<<<NP1 / 256, 256, 0, stream>>>(s1, rank1, NP2, NP1, kept1, perm1, vals1);
  pool_split_p<<<NP2, 64, 0, stream>>>(res1, perm1, vals1, x2h, x2l, 512);

  // augment1: materialize gathered packed operands, then dense exact GEMM (split-K)
  gather_p<<<(NP2 * NP1 / 8) / 256, 256, 0, stream>>>(B1rm, perm1, Gh, NP1 >> 5);
  gather_p<<<(NP2 * NP1 / 8) / 256, 256, 0, stream>>>(B1t, perm1, Hh, NP1 >> 5);
  gemm64<0, 0, 512, 4><<<dim3(8, 8, 4), 256, 0, stream>>>(Gh, nullptr, Hh, nullptr,
                                                          NP2, NP2, pscr);
  ep_aug<4><<<(NP2 * NP2) / 1024, 256, 0, stream>>>(pscr, B2, NP2);
  colsum_part<<<dim3(NP2 / 256, NP2 / 16), 256, 0, stream>>>(B2, deg2, NP2);
  dis_from_deg<<<NP2 / 256, 256, 0, stream>>>(deg2, dis2, NP2);
  tsplit_p<<<(NP2 * NP2 / 8) / 256, 256, 0, stream>>>(B2, B2th, B2tl, NP2, NP2);

  // gcn2 (bottleneck)
  gemm16<2, 1, 1, 512, 1><<<dim3(8, 16), 256, 0, stream>>>(x2h, x2l, Wt2h, Wt2l,
                                                           NP2, 512, dis2, nullptr, Y2th, Y2tl);
  gemm16<0, 1, 1, 512, 2><<<dim3(8, 16, 2), 256, 0, stream>>>(B2th, B2tl, Y2th, Y2tl,
                                                              NP2, 512, nullptr, pscr, nullptr, nullptr);
  ep3<2><<<(NP2 * 512) / 1024, 256, 0, stream>>>(pscr, dis2, b2, out2, NP2, 512);

  // up1
  unpool_split_p<<<(NP1 * 512 / 8) / 256, 256, 0, stream>>>(res1, out2, kept1, x3h, x3l, 512);
  gemm16<2, 1, 1, 512, 1><<<dim3(4, 32), 256, 0, stream>>>(x3h, x3l, Wt3h, Wt3l,
                                                           NP1, 256, dis1, nullptr, Y3th, Y3tl);
  gemm64<0, 1, 256, 8><<<dim3(2, 16, 8), 256, 0, stream>>>(B1t, nullptr, Y3th, Y3tl,
                                                           NP1, 256, pscr);
  ep3<8><<<(NP1 * 256) / 1024, 256, 0, stream>>>(pscr, dis1, b3, out3, NP1, 256);

  // up0
  unpool_split_p<<<(NN * 256 / 8) / 256, 256, 0, stream>>>(res0, out3, kept0, x4h, x4l, 256);
  gemm16<1, 1, 1, 256, 1><<<dim3(2, 64), 256, 0, stream>>>(x4h, x4l, Wt4h, Wt4l,
                                                           NN, 128, dis0, yreg, nullptr, nullptr);
  spmm_gather_v<128><<<NN / 4, 256, 0, stream>>>(yreg, csc_off, csc_src, dis0, b4, out);
}